// Round 6
// baseline (162.849 us; speedup 1.0000x reference)
//
#include <hip/hip_runtime.h>
#include <hip/hip_bf16.h>
#include <stdint.h>

#define T_   2048
#define DM_  1024
#define HD_  64
#define NROW 16384  // B*T
#define SPLIT 4     // kv-splits per q-tile (occupancy lever for attn)
#define BM   32     // proj rows per block
#define BK   64     // proj k per step

typedef __attribute__((ext_vector_type(8)))  __bf16 bf16x8;
typedef __attribute__((ext_vector_type(4)))  __bf16 bf16x4;
typedef __attribute__((ext_vector_type(4)))  float  f32x4;
typedef __attribute__((ext_vector_type(16))) float  f32x16;

// ---------------- kernel 0: pack [Wq|Wk|Wv] -> bf16 32x32x16 B-frag order -----
// wfrag[kc][t][lane][j] holds W[k = kc*16 + (lane>>5)*8 + j][n = t*32 + (lane&31)]
// kc: 0..63 (K16 blocks), t: 0..5 (n-tiles of 32; 0-1=Q, 2-3=K, 4-5=V)
__global__ void wconv_k(const float* __restrict__ Wq, const float* __restrict__ Wk,
                        const float* __restrict__ Wv, __bf16* __restrict__ wfrag) {
    int tid  = blockIdx.x * 256 + threadIdx.x;   // 24576 total
    int lane = tid & 63;
    int t    = (tid >> 6) % 6;
    int kc   = tid / (6 * 64);
    int n = t * 32 + (lane & 31);
    const float* W = (n < 64) ? Wq : (n < 128) ? Wk : Wv;
    int col = n & 63;
    int k0  = kc * 16 + (lane >> 5) * 8;
    __bf16* dst = wfrag + (size_t)tid * 8;
#pragma unroll
    for (int j = 0; j < 8; ++j) dst[j] = (__bf16)W[(k0 + j) * HD_ + col];
}

// ---------------- kernel 1: QKV projection GEMM (16384x192x1024) --------------
// 32x32x16 MFMA (4x fewer LDS bytes/flop than 16x16x32). 512 blocks x 384 thr
// (6 waves = 6 n-tiles of 32), BM=32, BK=64 double-buffered. A cvt'd via regs
// into frag-ordered LDS (16B linear writes); B DMA'd frag-ordered via
// global_load_lds. Every MFMA operand = one linear conflict-free ds_read_b128.
__global__ __launch_bounds__(384, 3) void proj_k(const float* __restrict__ x,
        const __bf16* __restrict__ wfrag, __bf16* __restrict__ Qb,
        __bf16* __restrict__ Kb, __bf16* __restrict__ Vt) {
    __shared__ __bf16 abuf[2][4][64][8];      // [buf][s][lane][j] A frags (8KB)
    __shared__ __bf16 bbuf[2][4][6][64][8];   // [buf][s][t][lane][j]   (48KB)
    int tid  = threadIdx.x;
    int lane = tid & 63, wave = tid >> 6;     // wave = n-tile 0..5
    int row0 = blockIdx.x * BM;
    // A staging role (tid<256): thread=(row, 8-col chunk) -> one frag 16B write
    bool stager = tid < 256;
    int srow = tid >> 3, sc8 = tid & 7;
    int s_sub = sc8 >> 1, s_lane = srow + 32 * (sc8 & 1);
    const float* xp0 = x + (size_t)(row0 + srow) * DM_ + sc8 * 8;

    f32x16 acc = (f32x16)0.f;

    // prologue: stage step 0 into buf 0
    {
#pragma unroll
        for (int i = 0; i < 4; ++i) {
            int ch = wave * 4 + i;            // 24 (s,t) chunks over 6 waves
            int s = ch / 6, t = ch % 6;
            const __bf16* src = wfrag + ((size_t)(0 * 4 + s) * 6 + t) * 512 + lane * 8;
            __builtin_amdgcn_global_load_lds(
                (const __attribute__((address_space(1))) void*)src,
                (__attribute__((address_space(3))) void*)&bbuf[0][s][t][0][0], 16, 0, 0);
        }
        if (stager) {
            f32x4 x0 = *(const f32x4*)(xp0);
            f32x4 x1 = *(const f32x4*)(xp0 + 4);
            bf16x8 a;
#pragma unroll
            for (int j = 0; j < 4; ++j) { a[j] = (__bf16)x0[j]; a[4 + j] = (__bf16)x1[j]; }
            *(bf16x8*)&abuf[0][s_sub][s_lane][0] = a;
        }
    }

    for (int kk = 0; kk < 16; ++kk) {
        int buf = kk & 1, nb = buf ^ 1;
        __syncthreads();                      // buf ready (ds_writes + DMA drained)
        f32x4 x0, x1;
        bool hn = (kk + 1) < 16;
        if (hn) {                             // prefetch next step into nb
#pragma unroll
            for (int i = 0; i < 4; ++i) {
                int ch = wave * 4 + i;
                int s = ch / 6, t = ch % 6;
                const __bf16* src = wfrag + ((size_t)((kk + 1) * 4 + s) * 6 + t) * 512 + lane * 8;
                __builtin_amdgcn_global_load_lds(
                    (const __attribute__((address_space(1))) void*)src,
                    (__attribute__((address_space(3))) void*)&bbuf[nb][s][t][0][0], 16, 0, 0);
            }
            if (stager) {
                const float* xp = xp0 + (kk + 1) * BK;
                x0 = *(const f32x4*)(xp);
                x1 = *(const f32x4*)(xp + 4);
            }
        }
#pragma unroll
        for (int s = 0; s < 4; ++s) {
            bf16x8 af = *(const bf16x8*)&abuf[buf][s][lane][0];
            bf16x8 bfh = *(const bf16x8*)&bbuf[buf][s][wave][lane][0];
            acc = __builtin_amdgcn_mfma_f32_32x32x16_bf16(af, bfh, acc, 0, 0, 0);
        }
        if (hn && stager) {                   // A cvt + frag write after compute
            bf16x8 a;
#pragma unroll
            for (int j = 0; j < 4; ++j) { a[j] = (__bf16)x0[j]; a[4 + j] = (__bf16)x1[j]; }
            *(bf16x8*)&abuf[nb][s_sub][s_lane][0] = a;
        }
    }

    // epilogue: 32x32 C layout col = lane&31, row = (r&3) + 8*(r>>2) + 4*(lane>>5)
    int n = wave * 32 + (lane & 31);          // wave-uniform branch selection
#pragma unroll
    for (int r = 0; r < 16; ++r) {
        int grow = row0 + (r & 3) + 8 * (r >> 2) + 4 * (lane >> 5);
        float v  = acc[r];
        // fold 1/sqrt(64) * log2(e) into Q so softmax runs in exp2 domain
        if (n < 64)       Qb[(size_t)grow * HD_ + n] = (__bf16)(v * 0.18033688f);
        else if (n < 128) Kb[(size_t)grow * HD_ + (n - 64)] = (__bf16)v;
        else              Vt[(size_t)(grow >> 11) * (HD_ * T_) + (size_t)(n - 128) * T_ + (grow & 2047)] = (__bf16)v;
    }
}

// ---------------- kernel 2: causal flash attention, kv-split partials --------
// 2048 blocks x 128 threads (2 waves x 16 q-rows; 4 kv-splits per q-tile).
// S^T = K*Q^T (q lane-local), online softmax in exp2 domain, P via per-wave LDS
// relayout, O^T = V^T * P^T. All 16 loads issued at iteration top; lsum kept as
// per-lane partial (al is wave-uniform) -> cross-lane sum deferred out of loop.
__global__ __launch_bounds__(128, 2) void attn_k(const __bf16* __restrict__ Qb,
        const __bf16* __restrict__ Kb, const __bf16* __restrict__ Vt,
        float* __restrict__ Opart, float* __restrict__ ml) {
    int split = blockIdx.x >> 9;
    int bid2  = blockIdx.x & 511;
    int half = bid2 >> 8, idx = bid2 & 255;
    int b = idx >> 5, p = idx & 31;
    int qb = half ? (63 - p) : p;            // pair big+small causal extents per CU
    int wave = threadIdx.x >> 6, lane = threadIdx.x & 63;
    int c = lane & 15, g = lane >> 4;
    int qg   = qb * 32 + wave * 16 + c;      // this lane's q row
    int tile = b * 128 + qb * 2 + wave;      // 16-row q-tile id (0..1023)
    int nd2  = (qb + 2) >> 1;                // double-tiles of 64 kv
    float m = -1e30f, lsum = 0.f;
    if (split < nd2) {
        const __bf16* qp = Qb + (size_t)(b * T_ + qg) * HD_ + g * 8;
        bf16x8 qf0 = *(const bf16x8*)qp;
        bf16x8 qf1 = *(const bf16x8*)(qp + 32);
        const __bf16* Kbase = Kb + (size_t)b * T_ * HD_;
        const __bf16* Vbase = Vt + (size_t)b * HD_ * T_;
        f32x4 o0 = (f32x4)0.f, o1 = (f32x4)0.f, o2 = (f32x4)0.f, o3 = (f32x4)0.f;
        __shared__ __bf16 plds[2][16][72];   // per-wave P tile (64 kv), rows padded
        __bf16 (*pl)[72] = plds[wave];
        for (int kt = split; kt < nd2; kt += SPLIT) {
            int kv0 = kt * 64;
            // ---- issue ALL loads up front: K (needed by QK) then V (needed late)
            const __bf16* kp = Kbase + (size_t)(kv0 + c) * HD_ + g * 8;
            bf16x8 ka00 = *(const bf16x8*)(kp);
            bf16x8 ka01 = *(const bf16x8*)(kp + 32);
            bf16x8 ka10 = *(const bf16x8*)(kp + 16 * HD_);
            bf16x8 ka11 = *(const bf16x8*)(kp + 16 * HD_ + 32);
            bf16x8 kb00 = *(const bf16x8*)(kp + 32 * HD_);
            bf16x8 kb01 = *(const bf16x8*)(kp + 32 * HD_ + 32);
            bf16x8 kb10 = *(const bf16x8*)(kp + 48 * HD_);
            bf16x8 kb11 = *(const bf16x8*)(kp + 48 * HD_ + 32);
            const __bf16* vp = Vbase + (size_t)c * T_ + kv0 + g * 8;
            bf16x8 v0a = *(const bf16x8*)(vp);
            bf16x8 v1a = *(const bf16x8*)(vp + 16 * T_);
            bf16x8 v2a = *(const bf16x8*)(vp + 32 * T_);
            bf16x8 v3a = *(const bf16x8*)(vp + 48 * T_);
            bf16x8 v0b = *(const bf16x8*)(vp + 32);
            bf16x8 v1b = *(const bf16x8*)(vp + 16 * T_ + 32);
            bf16x8 v2b = *(const bf16x8*)(vp + 32 * T_ + 32);
            bf16x8 v3b = *(const bf16x8*)(vp + 48 * T_ + 32);
            f32x4 sa0 = (f32x4)0.f, sa1 = (f32x4)0.f, sb0 = (f32x4)0.f, sb1 = (f32x4)0.f;
            sa0 = __builtin_amdgcn_mfma_f32_16x16x32_bf16(ka00, qf0, sa0, 0, 0, 0);
            sa0 = __builtin_amdgcn_mfma_f32_16x16x32_bf16(ka01, qf1, sa0, 0, 0, 0);
            sa1 = __builtin_amdgcn_mfma_f32_16x16x32_bf16(ka10, qf0, sa1, 0, 0, 0);
            sa1 = __builtin_amdgcn_mfma_f32_16x16x32_bf16(ka11, qf1, sa1, 0, 0, 0);
            sb0 = __builtin_amdgcn_mfma_f32_16x16x32_bf16(kb00, qf0, sb0, 0, 0, 0);
            sb0 = __builtin_amdgcn_mfma_f32_16x16x32_bf16(kb01, qf1, sb0, 0, 0, 0);
            sb1 = __builtin_amdgcn_mfma_f32_16x16x32_bf16(kb10, qf0, sb1, 0, 0, 0);
            sb1 = __builtin_amdgcn_mfma_f32_16x16x32_bf16(kb11, qf1, sb1, 0, 0, 0);
            float s[16];
#pragma unroll
            for (int r = 0; r < 4; ++r) {
                s[r] = sa0[r]; s[4 + r] = sa1[r]; s[8 + r] = sb0[r]; s[12 + r] = sb1[r];
            }
            if (kt == nd2 - 1) {             // only the final double-tile needs masking
#pragma unroll
                for (int i = 0; i < 16; ++i) {
                    int kv = kv0 + (i >> 2) * 16 + g * 4 + (i & 3);
                    if (kv > qg) s[i] = -1e30f;
                }
            }
            // tree max (depth 4)
            float m0 = fmaxf(fmaxf(s[0], s[1]), fmaxf(s[2], s[3]));
            float m1 = fmaxf(fmaxf(s[4], s[5]), fmaxf(s[6], s[7]));
            float m2 = fmaxf(fmaxf(s[8], s[9]), fmaxf(s[10], s[11]));
            float m3 = fmaxf(fmaxf(s[12], s[13]), fmaxf(s[14], s[15]));
            float tm = fmaxf(fmaxf(m0, m1), fmaxf(m2, m3));
            tm = fmaxf(tm, __shfl_xor(tm, 16));
            tm = fmaxf(tm, __shfl_xor(tm, 32));
            float mn = fmaxf(m, tm);
            float al = __builtin_amdgcn_exp2f(m - mn);
#pragma unroll
            for (int i = 0; i < 16; ++i) s[i] = __builtin_amdgcn_exp2f(s[i] - mn);
            // per-lane partial sum only (cross-lane sum deferred out of the loop;
            // al is wave-uniform so the partials rescale identically)
            float p0 = (s[0] + s[1]) + (s[2] + s[3]);
            float p1 = (s[4] + s[5]) + (s[6] + s[7]);
            float p2 = (s[8] + s[9]) + (s[10] + s[11]);
            float p3 = (s[12] + s[13]) + (s[14] + s[15]);
            float ps = (p0 + p1) + (p2 + p3);
            lsum = lsum * al + ps;
            m = mn;
            o0 *= al; o1 *= al; o2 *= al; o3 *= al;
            // P (this lane: q=c, kv = (i>>2)*16 + g*4 + (i&3)) -> LDS as P[q][kv]
#pragma unroll
            for (int mt = 0; mt < 4; ++mt) {
                bf16x4 pv;
#pragma unroll
                for (int r = 0; r < 4; ++r) pv[r] = (__bf16)s[mt * 4 + r];
                *(bf16x4*)&pl[c][mt * 16 + g * 4] = pv;
            }
            // B-frag reads: P[q=c][kv = tile*32 + g*8 + j], wave-private (no barrier)
            bf16x8 pf0 = *(const bf16x8*)&pl[c][g * 8];
            bf16x8 pf1 = *(const bf16x8*)&pl[c][32 + g * 8];
            o0 = __builtin_amdgcn_mfma_f32_16x16x32_bf16(v0a, pf0, o0, 0, 0, 0);
            o1 = __builtin_amdgcn_mfma_f32_16x16x32_bf16(v1a, pf0, o1, 0, 0, 0);
            o2 = __builtin_amdgcn_mfma_f32_16x16x32_bf16(v2a, pf0, o2, 0, 0, 0);
            o3 = __builtin_amdgcn_mfma_f32_16x16x32_bf16(v3a, pf0, o3, 0, 0, 0);
            o0 = __builtin_amdgcn_mfma_f32_16x16x32_bf16(v0b, pf1, o0, 0, 0, 0);
            o1 = __builtin_amdgcn_mfma_f32_16x16x32_bf16(v1b, pf1, o1, 0, 0, 0);
            o2 = __builtin_amdgcn_mfma_f32_16x16x32_bf16(v2b, pf1, o2, 0, 0, 0);
            o3 = __builtin_amdgcn_mfma_f32_16x16x32_bf16(v3b, pf1, o3, 0, 0, 0);
        }
        // partial O^T store: Opart[part][q_local=c][d = dt*16 + g*4 + r]
        float* op = Opart + ((size_t)tile * SPLIT + split) * 1024 + c * 64 + g * 4;
        *(f32x4*)(op)      = o0;
        *(f32x4*)(op + 16) = o1;
        *(f32x4*)(op + 32) = o2;
        *(f32x4*)(op + 48) = o3;
    }
    // deferred cross-lane lsum reduction (2 shuffles total, not per-iter)
    lsum += __shfl_xor(lsum, 16);
    lsum += __shfl_xor(lsum, 32);
    if (g == 0) {                            // (m, l) per q row; l==0 marks empty split
        float* mlp = ml + ((size_t)tile * SPLIT + split) * 32 + c * 2;
        mlp[0] = m; mlp[1] = lsum;
    }
}

// ---------------- kernel 3: merge kv-split partials, normalize, mask ---------
// 1024 blocks x 256 threads; block = one 16-row q-tile; thread = (q, 4 d's).
__global__ __launch_bounds__(256) void comb_k(const float* __restrict__ Opart,
        const float* __restrict__ ml, const int* __restrict__ vlen,
        float* __restrict__ out) {
    int tile = blockIdx.x;
    int b  = tile >> 7;
    int q0 = (tile & 127) * 16;
    int q  = threadIdx.x >> 4;
    int d0 = (threadIdx.x & 15) * 4;
    int qg = q0 + q;
    const float* mlp = ml + (size_t)tile * SPLIT * 32 + q * 2;
    float mj[SPLIT], lj[SPLIT];
#pragma unroll
    for (int j = 0; j < SPLIT; ++j) { mj[j] = mlp[j * 32]; lj[j] = mlp[j * 32 + 1]; }
    float M = fmaxf(fmaxf(mj[0], mj[1]), fmaxf(mj[2], mj[3]));
    f32x4 acc = (f32x4)0.f;
    float L = 0.f;
#pragma unroll
    for (int j = 0; j < SPLIT; ++j) {
        if (lj[j] > 0.f) {                   // skip empty splits (Opart unwritten there)
            float sc = __builtin_amdgcn_exp2f(mj[j] - M);
            L += lj[j] * sc;
            f32x4 ov = *(const f32x4*)(Opart + ((size_t)tile * SPLIT + j) * 1024 + q * 64 + d0);
            acc += ov * sc;
        }
    }
    float inv = (qg < vlen[b]) ? 1.f / L : 0.f;  // dead rows -> 0
    f32x4 r = acc * inv;
    *(f32x4*)(out + ((size_t)(b * T_) + qg) * HD_ + d0) = r;
}

extern "C" void kernel_launch(void* const* d_in, const int* in_sizes, int n_in,
                              void* d_out, int out_size, void* d_ws, size_t ws_size,
                              hipStream_t stream) {
    const float* x   = (const float*)d_in[0];
    const float* Wq  = (const float*)d_in[1];
    const float* Wk  = (const float*)d_in[2];
    const float* Wv  = (const float*)d_in[3];
    const int*   vln = (const int*)d_in[4];
    float* out = (float*)d_out;

    __bf16* Qb    = (__bf16*)d_ws;                 // 16384*64 bf16 = 2MB
    __bf16* Kb    = Qb + (size_t)NROW * HD_;       // 2MB
    __bf16* Vt    = Kb + (size_t)NROW * HD_;       // 2MB (V transposed per batch: [b][d][t])
    __bf16* wfrag = Vt + (size_t)NROW * HD_;       // 384KB frag-ordered weights
    float*  Opart = (float*)(wfrag + 24576 * 8);   // 1024 tiles x 4 splits x 16x64 f32 = 16MB
    float*  mlbuf = Opart + (size_t)1024 * SPLIT * 1024;  // 512KB (m,l) pairs

    wconv_k<<<96, 256, 0, stream>>>(Wq, Wk, Wv, wfrag);
    proj_k <<<512, 384, 0, stream>>>(x, wfrag, Qb, Kb, Vt);
    attn_k <<<512 * SPLIT, 128, 0, stream>>>(Qb, Kb, Vt, Opart, mlbuf);
    comb_k <<<1024, 256, 0, stream>>>(Opart, mlbuf, vln, out);
}

// Round 7
// 156.132 us; speedup vs baseline: 1.0430x; 1.0430x over previous
//
#include <hip/hip_runtime.h>
#include <hip/hip_bf16.h>
#include <stdint.h>

#define T_   2048
#define DM_  1024
#define HD_  64
#define NROW 16384  // B*T
#define SPLIT 8     // kv-splits per 32-row q-tile
#define BM   32     // proj rows per block
#define BK   64     // proj k per step

typedef __attribute__((ext_vector_type(8)))  __bf16 bf16x8;
typedef __attribute__((ext_vector_type(4)))  __bf16 bf16x4;
typedef __attribute__((ext_vector_type(4)))  float  f32x4;
typedef __attribute__((ext_vector_type(16))) float  f32x16;
typedef __attribute__((ext_vector_type(4)))  unsigned int u32x4;

static __device__ __forceinline__ unsigned pk2(float a, float b) {
    unsigned short ua = __builtin_bit_cast(unsigned short, (__bf16)a);
    unsigned short ub = __builtin_bit_cast(unsigned short, (__bf16)b);
    return (unsigned)ua | ((unsigned)ub << 16);
}

// ---------------- kernel 0: pack [Wq|Wk|Wv] -> bf16 16x16x32 B-frag order -----
// frag: ((kc*12 + t)*64 + lane)*8 + j holds W[k = kc*32 + (lane>>4)*8 + j][n = t*16 + (lane&15)]
__global__ void wconv_k(const float* __restrict__ Wq, const float* __restrict__ Wk,
                        const float* __restrict__ Wv, __bf16* __restrict__ wfrag) {
    int tid  = blockIdx.x * 256 + threadIdx.x;   // 24576 total
    int lane = tid & 63;
    int t    = (tid >> 6) % 12;
    int kc   = tid / (12 * 64);
    int c = lane & 15, g = lane >> 4;
    int n = t * 16 + c;
    const float* W = (n < 64) ? Wq : (n < 128) ? Wk : Wv;
    int col = n & 63;
    int k0  = kc * 32 + g * 8;
    __bf16* dst = wfrag + (size_t)tid * 8;
#pragma unroll
    for (int j = 0; j < 8; ++j) dst[j] = (__bf16)W[(k0 + j) * HD_ + col];
}

// ---------------- kernel 1: QKV projection GEMM (16384x192x1024, 16x16x32) ----
// Proven R4/R5 structure: coalesced x->LDS (padded), wfrag->LDS via
// global_load_lds. 512 blocks x 256 thr, 2 blocks/CU.
__global__ __launch_bounds__(256, 2) void proj_k(const float* __restrict__ x,
        const __bf16* __restrict__ wfrag, __bf16* __restrict__ Qb,
        __bf16* __restrict__ Kb, __bf16* __restrict__ Vt) {
    __shared__ __bf16 abuf[2][BM][72];        // A tile bf16, row-padded (+8)
    __shared__ __bf16 bbuf[2][2][12][512];    // [buf][khalf][t][lane*8] frag order
    int tid  = threadIdx.x;
    int lane = tid & 63, wave = tid >> 6;
    int mh = wave >> 1, th = wave & 1;        // wave = 16-row half x 6-t half
    int c = lane & 15, g = lane >> 4;
    int row0 = blockIdx.x * BM;
    int ar = tid >> 3, a0 = (tid & 7) * 8;    // staging: thread = (row, 8-col chunk)
    const float* xrow = x + (size_t)(row0 + ar) * DM_ + a0;

    f32x4 acc[6];
#pragma unroll
    for (int t = 0; t < 6; ++t) acc[t] = (f32x4)0.f;

    {   // prologue: stage step 0 into buf 0
#pragma unroll
        for (int i = 0; i < 6; ++i) {
            int p = wave * 6 + i;
            int kh = p / 12, tt = p % 12;
            const __bf16* src = wfrag + ((size_t)kh * 12 + tt) * 512 + lane * 8;
            __builtin_amdgcn_global_load_lds(
                (const __attribute__((address_space(1))) void*)src,
                (__attribute__((address_space(3))) void*)&bbuf[0][kh][tt][0], 16, 0, 0);
        }
        f32x4 x0 = *(const f32x4*)(xrow);
        f32x4 x1 = *(const f32x4*)(xrow + 4);
        bf16x8 a;
#pragma unroll
        for (int j = 0; j < 4; ++j) { a[j] = (__bf16)x0[j]; a[4 + j] = (__bf16)x1[j]; }
        *(bf16x8*)&abuf[0][ar][a0] = a;
    }

    for (int kk = 0; kk < 16; ++kk) {
        int buf = kk & 1, nb = buf ^ 1;
        __syncthreads();
        f32x4 x0, x1;
        bool hn = (kk + 1) < 16;
        if (hn) {
            const float* xp = xrow + (kk + 1) * BK;
            x0 = *(const f32x4*)(xp);
            x1 = *(const f32x4*)(xp + 4);
#pragma unroll
            for (int i = 0; i < 6; ++i) {
                int p = wave * 6 + i;
                int kh = p / 12, tt = p % 12;
                const __bf16* src = wfrag + (((size_t)(kk + 1) * 2 + kh) * 12 + tt) * 512 + lane * 8;
                __builtin_amdgcn_global_load_lds(
                    (const __attribute__((address_space(1))) void*)src,
                    (__attribute__((address_space(3))) void*)&bbuf[nb][kh][tt][0], 16, 0, 0);
            }
        }
#pragma unroll
        for (int kh = 0; kh < 2; ++kh) {
            bf16x8 af = *(const bf16x8*)&abuf[buf][mh * 16 + c][kh * 32 + g * 8];
#pragma unroll
            for (int t = 0; t < 6; ++t) {
                bf16x8 bfh = *(const bf16x8*)&bbuf[buf][kh][th * 6 + t][lane * 8];
                acc[t] = __builtin_amdgcn_mfma_f32_16x16x32_bf16(af, bfh, acc[t], 0, 0, 0);
            }
        }
        if (hn) {
            bf16x8 a;
#pragma unroll
            for (int j = 0; j < 4; ++j) { a[j] = (__bf16)x0[j]; a[4 + j] = (__bf16)x1[j]; }
            *(bf16x8*)&abuf[nb][ar][a0] = a;
        }
    }

    // epilogue: C col = lane&15 (n within t), row = (lane>>4)*4 + r
#pragma unroll
    for (int t = 0; t < 6; ++t) {
        int tg = th * 6 + t;
        int n  = tg * 16 + c;
#pragma unroll
        for (int r = 0; r < 4; ++r) {
            int grow = row0 + mh * 16 + g * 4 + r;
            float v  = acc[t][r];
            // fold 1/sqrt(64)*log2(e) into Q -> softmax in exp2 domain
            if (n < 64)       Qb[(size_t)grow * HD_ + n] = (__bf16)(v * 0.18033688f);
            else if (n < 128) Kb[(size_t)grow * HD_ + (n - 64)] = (__bf16)v;
            else              Vt[(size_t)(grow >> 11) * (HD_ * T_) + (size_t)(n - 128) * T_ + (grow & 2047)] = (__bf16)v;
        }
    }
}

// ---------------- kernel 2: causal flash attention, 32x32 all-register -------
// 4096 blocks x 64 thr (1 wave; 8 kv-splits x 512 q-tiles of 32 rows).
// S^T = K*Q^T via mfma_32x32x16 (lane owns q=lane&31); softmax lane-local +
// one shfl_xor(32); P packed to bf16 in-register and redistributed into PV
// B-frags with 2 shfl_xor(32) per k-sub. Zero LDS, zero barriers.
// Frag layouts (verified by passing R6 proj): A[m=lane&31][k=(lane>>5)*8+j],
// B[k=(lane>>5)*8+j][n=lane&31], C col=lane&31, row=(r&3)+8*(r>>2)+4*(lane>>5).
__global__ __launch_bounds__(64, 3) void attn_k(const __bf16* __restrict__ Qb,
        const __bf16* __restrict__ Kb, const __bf16* __restrict__ Vt,
        float* __restrict__ Opart, float* __restrict__ ml) {
    int split = blockIdx.x >> 9;
    int rest  = blockIdx.x & 511;
    int b = rest >> 6, p = rest & 63;
    int qt = (p & 1) ? (63 - (p >> 1)) : (p >> 1);   // pair big+small extents
    int lane = threadIdx.x & 63;
    int low = lane & 31, h = lane >> 5;
    int q0 = qt * 32, qg = q0 + low;                 // this lane's q row
    int t32 = b * 64 + qt;
    int nd = qt + 1;                                 // kv-tiles of 32
    float m = -1e30f, lsum = 0.f;
    f32x16 oa = (f32x16)0.f, ob = (f32x16)0.f;       // O^T d-halves [d][q]
    if (split < nd) {
        const __bf16* qp = Qb + (size_t)(b * T_ + qg) * HD_ + h * 8;
        bf16x8 qf0 = *(const bf16x8*)(qp);
        bf16x8 qf1 = *(const bf16x8*)(qp + 16);
        bf16x8 qf2 = *(const bf16x8*)(qp + 32);
        bf16x8 qf3 = *(const bf16x8*)(qp + 48);
        const __bf16* Kbase = Kb + (size_t)b * T_ * HD_;
        const __bf16* Vbase = Vt + (size_t)b * HD_ * T_;
        for (int kt = split; kt < nd; kt += SPLIT) {
            int kv0 = kt * 32;
            const __bf16* kp = Kbase + (size_t)(kv0 + low) * HD_ + h * 8;
            bf16x8 kf0 = *(const bf16x8*)(kp);
            bf16x8 kf1 = *(const bf16x8*)(kp + 16);
            bf16x8 kf2 = *(const bf16x8*)(kp + 32);
            bf16x8 kf3 = *(const bf16x8*)(kp + 48);
            const __bf16* vp = Vbase + (size_t)low * T_ + kv0 + h * 8;
            bf16x8 va00 = *(const bf16x8*)(vp);              // dh=0, s2=0
            bf16x8 va01 = *(const bf16x8*)(vp + 16);         // dh=0, s2=1
            bf16x8 va10 = *(const bf16x8*)(vp + (size_t)32 * T_);
            bf16x8 va11 = *(const bf16x8*)(vp + (size_t)32 * T_ + 16);
            f32x16 st = (f32x16)0.f;                         // S^T[kv_l][q]
            st = __builtin_amdgcn_mfma_f32_32x32x16_bf16(kf0, qf0, st, 0, 0, 0);
            st = __builtin_amdgcn_mfma_f32_32x32x16_bf16(kf1, qf1, st, 0, 0, 0);
            st = __builtin_amdgcn_mfma_f32_32x32x16_bf16(kf2, qf2, st, 0, 0, 0);
            st = __builtin_amdgcn_mfma_f32_32x32x16_bf16(kf3, qf3, st, 0, 0, 0);
            if (kt == nd - 1) {                              // diagonal tile mask
#pragma unroll
                for (int r = 0; r < 16; ++r) {
                    int kv = kv0 + (r & 3) + 8 * (r >> 2) + 4 * h;
                    if (kv > qg) st[r] = -1e30f;
                }
            }
            // per-q max: lane-local 16 (tree) + partner half via 1 shfl
            float t0 = fmaxf(fmaxf(st[0], st[1]), fmaxf(st[2], st[3]));
            float t1 = fmaxf(fmaxf(st[4], st[5]), fmaxf(st[6], st[7]));
            float t2 = fmaxf(fmaxf(st[8], st[9]), fmaxf(st[10], st[11]));
            float t3 = fmaxf(fmaxf(st[12], st[13]), fmaxf(st[14], st[15]));
            float tm = fmaxf(fmaxf(t0, t1), fmaxf(t2, t3));
            tm = fmaxf(tm, __shfl_xor(tm, 32));
            float mn = fmaxf(m, tm);
            float al = __builtin_amdgcn_exp2f(m - mn);
            m = mn;
#pragma unroll
            for (int r = 0; r < 16; ++r) st[r] = __builtin_amdgcn_exp2f(st[r] - mn);
            float s0 = (st[0] + st[1]) + (st[2] + st[3]);
            float s1 = (st[4] + st[5]) + (st[6] + st[7]);
            float s2s = (st[8] + st[9]) + (st[10] + st[11]);
            float s3 = (st[12] + st[13]) + (st[14] + st[15]);
            lsum = lsum * al + ((s0 + s1) + (s2s + s3));     // cross-half deferred
            oa *= al; ob *= al;
            // P -> bf16 B-frags: lane holds P[q=low][kv_l=(r&3)+8(r>>2)+4h];
            // frag(s2) j <-> kv_l = 16*s2+8h+j; halves swap via shfl_xor(32).
#pragma unroll
            for (int s2 = 0; s2 < 2; ++s2) {
                int base = 8 * s2;
                unsigned w0 = pk2(st[base + 0], st[base + 1]);
                unsigned w1 = pk2(st[base + 2], st[base + 3]);
                unsigned w2 = pk2(st[base + 4], st[base + 5]);
                unsigned w3 = pk2(st[base + 6], st[base + 7]);
                unsigned x0 = h ? w0 : w2, x1 = h ? w1 : w3;
                unsigned r0 = (unsigned)__shfl_xor((int)x0, 32);
                unsigned r1 = (unsigned)__shfl_xor((int)x1, 32);
                u32x4 wv;
                wv.x = h ? r0 : w0; wv.y = h ? r1 : w1;
                wv.z = h ? w2 : r0; wv.w = h ? w3 : r1;
                bf16x8 pf = __builtin_bit_cast(bf16x8, wv);
                if (s2 == 0) {
                    oa = __builtin_amdgcn_mfma_f32_32x32x16_bf16(va00, pf, oa, 0, 0, 0);
                    ob = __builtin_amdgcn_mfma_f32_32x32x16_bf16(va10, pf, ob, 0, 0, 0);
                } else {
                    oa = __builtin_amdgcn_mfma_f32_32x32x16_bf16(va01, pf, oa, 0, 0, 0);
                    ob = __builtin_amdgcn_mfma_f32_32x32x16_bf16(va11, pf, ob, 0, 0, 0);
                }
            }
        }
        // partial store O^T: [d][q] rows of 32 floats
        float* op = Opart + ((size_t)t32 * SPLIT + split) * 2048;
#pragma unroll
        for (int r = 0; r < 16; ++r) {
            int d = (r & 3) + 8 * (r >> 2) + 4 * h;
            op[d * 32 + low]        = oa[r];
            op[(d + 32) * 32 + low] = ob[r];
        }
    }
    lsum += __shfl_xor(lsum, 32);
    if (h == 0) {                                    // (m,l) per q; l==0 = empty
        float* mlp = ml + ((size_t)t32 * SPLIT + split) * 64 + low * 2;
        mlp[0] = m; mlp[1] = lsum;
    }
}

// ---------------- kernel 3: merge kv-split partials, normalize, mask ---------
// 512 blocks x 256 thr; block = one 32-row q-tile; unit = (q, 4 d's) x2.
__global__ __launch_bounds__(256) void comb_k(const float* __restrict__ Opart,
        const float* __restrict__ ml, const int* __restrict__ vlen,
        float* __restrict__ out) {
    int t32 = blockIdx.x;
    int b = t32 >> 6, q0 = (t32 & 63) * 32;
    int vl = vlen[b];
#pragma unroll
    for (int u = threadIdx.x; u < 512; u += 256) {
        int q = u & 31, dq = u >> 5;                 // dq 0..15
        const float* mlp = ml + (size_t)t32 * SPLIT * 64 + q * 2;
        float mj[SPLIT], lj[SPLIT];
#pragma unroll
        for (int j = 0; j < SPLIT; ++j) { mj[j] = mlp[j * 64]; lj[j] = mlp[j * 64 + 1]; }
        float M = mj[0];
#pragma unroll
        for (int j = 1; j < SPLIT; ++j) M = fmaxf(M, mj[j]);
        f32x4 acc = (f32x4)0.f;
        float L = 0.f;
#pragma unroll
        for (int j = 0; j < SPLIT; ++j) {
            float sc = __builtin_amdgcn_exp2f(mj[j] - M);  // 0 for empty splits
            L += lj[j] * sc;
            const float* op = Opart + ((size_t)t32 * SPLIT + j) * 2048 + dq * 128 + q;
            acc[0] += op[0]  * sc;
            acc[1] += op[32] * sc;
            acc[2] += op[64] * sc;
            acc[3] += op[96] * sc;
        }
        float inv = (q0 + q < vl) ? 1.f / L : 0.f;   // dead rows -> 0
        *(f32x4*)(out + ((size_t)(b * T_) + q0 + q) * HD_ + dq * 4) = acc * inv;
    }
}

extern "C" void kernel_launch(void* const* d_in, const int* in_sizes, int n_in,
                              void* d_out, int out_size, void* d_ws, size_t ws_size,
                              hipStream_t stream) {
    const float* x   = (const float*)d_in[0];
    const float* Wq  = (const float*)d_in[1];
    const float* Wk  = (const float*)d_in[2];
    const float* Wv  = (const float*)d_in[3];
    const int*   vln = (const int*)d_in[4];
    float* out = (float*)d_out;

    __bf16* Qb    = (__bf16*)d_ws;                 // 2MB
    __bf16* Kb    = Qb + (size_t)NROW * HD_;       // 2MB
    __bf16* Vt    = Kb + (size_t)NROW * HD_;       // 2MB ([b][d][t])
    __bf16* wfrag = Vt + (size_t)NROW * HD_;       // 384KB
    float*  Opart = (float*)(wfrag + 24576 * 8);   // 512 x 8 x 2048 f32 = 32MB
    float*  mlbuf = Opart + (size_t)512 * SPLIT * 2048;  // 1MB

    wconv_k<<<96, 256, 0, stream>>>(Wq, Wk, Wv, wfrag);
    proj_k <<<512, 256, 0, stream>>>(x, wfrag, Qb, Kb, Vt);
    attn_k <<<512 * SPLIT, 64, 0, stream>>>(Qb, Kb, Vt, Opart, mlbuf);
    comb_k <<<512, 256, 0, stream>>>(Opart, mlbuf, vln, out);
}